// Round 5
// baseline (84.876 us; speedup 1.0000x reference)
//
#include <hip/hip_runtime.h>

#define HH 256
#define WW 256
#define CC 32
#define K 7
#define RAD 3
#define TSX 16
#define TSY 8
#define HX (TSX + K - 1)   /* 22 */
#define HY (TSY + K - 1)   /* 14 */
#define NPIX (HX * HY)     /* 308 */
#define REF_ST 40          /* halfs per pixel (32 ch + 8 pad), 80 B: keeps b128 16B-aligned */
#define REF_SZ 12800       /* >= max masked OOB read (pixel 317)*40 + 32 + 8 */
#define VT_ST 344          /* halfs per channel row of V^T (14*24 + 8 pad) */
#define VT_SZ 11008        /* 32 * 344 */
#define NTHREADS 256

typedef _Float16 half_t;
typedef _Float16 h8 __attribute__((ext_vector_type(8)));
typedef float f4 __attribute__((ext_vector_type(4)));
typedef unsigned int u32;
typedef u32 u4v __attribute__((ext_vector_type(4)));
typedef u32 u2v __attribute__((ext_vector_type(2)));

union Frag { h8 h; u4v u; u32 w[4]; };

static __device__ inline u32 pkrtz_u(float x, float y) {
    auto t = __builtin_amdgcn_cvt_pkrtz(x, y);
    u32 r; __builtin_memcpy(&r, &t, sizeof(r)); return r;
}

__global__ __launch_bounds__(NTHREADS) void local_attn_mfma(
    const float* __restrict__ main_in,
    const float* __restrict__ ref_in,
    const float* __restrict__ val_in,
    float* __restrict__ out)
{
    // s_ref: [pixel][ch] fp16, stride 40 halfs (no swizzle — a +32-half offset
    //        overlapped neighboring pixels and raced; 4-way a-quad bank conflict
    //        on QK A-frag reads is ~1.58x on ~1us of LDS traffic, acceptable)
    // s_valT: [ch][hy][x] fp16 (x-stride 24, ch-stride 344) for PV's A=V^T b128 reads
    __shared__ half_t s_ref[REF_SZ];
    __shared__ half_t s_valT[VT_SZ];

    const int tid = threadIdx.x;
    const int ox = blockIdx.x * TSX;
    const int oy = blockIdx.y * TSY;

    // Zero both: un-staged gaps must be finite (NaN * 0 = NaN inside MFMA),
    // and masked-row reads past pixel 307 must stay in-array and finite.
    for (int j = tid; j < REF_SZ / 2; j += NTHREADS) ((u32*)s_ref)[j] = 0u;
    for (int j = tid; j < VT_SZ / 2; j += NTHREADS) ((u32*)s_valT)[j] = 0u;
    __syncthreads();

    // ---- Stage halo: ref -> s_ref (packed b64 writes), val -> s_valT (transposed u16 writes)
    for (int idx = tid; idx < NPIX * 8; idx += NTHREADS) {
        const int pix = idx >> 3;
        const int c4 = idx & 7;
        const int hy = pix / HX;
        const int wx = pix - hy * HX;
        const int gh = oy + hy - RAD;
        const int gw = ox + wx - RAD;
        u32 r0 = 0, r1 = 0;
        f4 v = {0.f, 0.f, 0.f, 0.f};
        if ((unsigned)gh < (unsigned)HH && (unsigned)gw < (unsigned)WW) {
            const int goff = (gh * WW + gw) * CC + c4 * 4;
            f4 rv = *(const f4*)(ref_in + goff);
            v = *(const f4*)(val_in + goff);
            r0 = pkrtz_u(rv.x, rv.y);
            r1 = pkrtz_u(rv.z, rv.w);
        }
        u2v rw = {r0, r1};
        *(u2v*)(s_ref + pix * REF_ST + c4 * 4) = rw;
        const int ch = c4 * 4;
        const int vo = hy * 24 + wx;
        s_valT[(ch + 0) * VT_ST + vo] = (half_t)v.x;
        s_valT[(ch + 1) * VT_ST + vo] = (half_t)v.y;
        s_valT[(ch + 2) * VT_ST + vo] = (half_t)v.z;
        s_valT[(ch + 3) * VT_ST + vo] = (half_t)v.w;
    }
    __syncthreads();

    // ---- Per-wave: 2 image rows, 16 queries each, all via MFMA ----
    const int lane = tid & 63;
    const int i = lane & 15;          // query column / A-row index
    const int g = lane >> 4;          // k-octet group
    const int k0 = 8 * (i >> 2) + (i & 3);  // permuted A-row -> key map (makes P lane-local)
    const int d0 = 8 * g - i;         // key - query offset for reg 0 of c1a
    const int wv = tid >> 6;

#pragma unroll 1
    for (int rrow = 0; rrow < 2; ++rrow) {
        const int hl = 2 * wv + rrow;
        const int h = oy + hl;

        // Q fragment (B-operand): lane holds query pixel (ox+i), channels 8g..8g+7
        const float* qp = main_in + (h * WW + ox + i) * CC + g * 8;
        f4 q0 = *(const f4*)qp;
        f4 q1 = *(const f4*)(qp + 4);
        Frag qf;
        qf.w[0] = pkrtz_u(q0.x, q0.y);
        qf.w[1] = pkrtz_u(q0.z, q0.w);
        qf.w[2] = pkrtz_u(q1.x, q1.y);
        qf.w[3] = pkrtz_u(q1.z, q1.w);

        // Scores: per di, C[key, query] = K-rows x Q. Band-mask to -inf.
        float sc[K][8];
#pragma unroll
        for (int di = 0; di < K; ++di) {
            const int rb = (hl + di) * HX;
            const int p0 = rb + k0;
            const int p1 = p0 + 4;
            Frag a0, a1;
            a0.u = *(const u4v*)(s_ref + p0 * REF_ST + g * 8);
            a1.u = *(const u4v*)(s_ref + p1 * REF_ST + g * 8);
            f4 c1a = {0.f, 0.f, 0.f, 0.f};
            f4 c1b = {0.f, 0.f, 0.f, 0.f};
            c1a = __builtin_amdgcn_mfma_f32_16x16x32_f16(a0.h, qf.h, c1a, 0, 0, 0);
            c1b = __builtin_amdgcn_mfma_f32_16x16x32_f16(a1.h, qf.h, c1b, 0, 0, 0);
#pragma unroll
            for (int r = 0; r < 4; ++r) {
                // c1a reg r = key halo-x 8g+r; c1b reg r = key 8g+4+r (via k0 permutation)
                sc[di][r]     = ((unsigned)(d0 + r) <= 6u)     ? c1a[r] : -1e30f;
                sc[di][r + 4] = ((unsigned)(d0 + 4 + r) <= 6u) ? c1b[r] : -1e30f;
            }
        }

        // Softmax over 49 in-band entries (image-OOB keys staged as 0 -> score 0, included)
        float mx = -1e30f;
#pragma unroll
        for (int di = 0; di < K; ++di)
#pragma unroll
            for (int j = 0; j < 8; ++j) mx = fmaxf(mx, sc[di][j]);
        mx = fmaxf(mx, __shfl_xor(mx, 16));
        mx = fmaxf(mx, __shfl_xor(mx, 32));
        float lsum = 0.f;
#pragma unroll
        for (int di = 0; di < K; ++di)
#pragma unroll
            for (int j = 0; j < 8; ++j) {
                const float ev = __expf(sc[di][j] - mx);  // masked -> exp(-inf) = 0
                sc[di][j] = ev;
                lsum += ev;
            }
        lsum += __shfl_xor(lsum, 16);
        lsum += __shfl_xor(lsum, 32);
        const float invl = 1.0f / lsum;   // lsum >= 1, safe

        // PV: C2[ch, query] += V^T(A) x P(B), accumulated over di
        f4 c2a = {0.f, 0.f, 0.f, 0.f};
        f4 c2b = {0.f, 0.f, 0.f, 0.f};
#pragma unroll
        for (int di = 0; di < K; ++di) {
            Frag pf;   // B-frag: half j = P[key 8g+j] -- lane-local thanks to k0 permutation
            pf.w[0] = pkrtz_u(sc[di][0], sc[di][1]);
            pf.w[1] = pkrtz_u(sc[di][2], sc[di][3]);
            pf.w[2] = pkrtz_u(sc[di][4], sc[di][5]);
            pf.w[3] = pkrtz_u(sc[di][6], sc[di][7]);
            const int ro = (hl + di) * 24 + g * 8;
            Frag va0, va1;
            va0.u = *(const u4v*)(s_valT + i * VT_ST + ro);          // ch i, keys 8g..8g+7
            va1.u = *(const u4v*)(s_valT + (i + 16) * VT_ST + ro);   // ch i+16
            c2a = __builtin_amdgcn_mfma_f32_16x16x32_f16(va0.h, pf.h, c2a, 0, 0, 0);
            c2b = __builtin_amdgcn_mfma_f32_16x16x32_f16(va1.h, pf.h, c2b, 0, 0, 0);
        }

        // C2 lane: col = query i, rows = ch 4g+r (frag a) / 16+4g+r (frag b)
        float* op = out + (h * WW + ox + i) * CC;
        f4 o0 = {c2a[0] * invl, c2a[1] * invl, c2a[2] * invl, c2a[3] * invl};
        f4 o1 = {c2b[0] * invl, c2b[1] * invl, c2b[2] * invl, c2b[3] * invl};
        *(f4*)(op + 4 * g) = o0;
        *(f4*)(op + 16 + 4 * g) = o1;
    }
}

extern "C" void kernel_launch(void* const* d_in, const int* in_sizes, int n_in,
                              void* d_out, int out_size, void* d_ws, size_t ws_size,
                              hipStream_t stream) {
    const float* main_in = (const float*)d_in[0];
    const float* ref_in  = (const float*)d_in[1];
    const float* val_in  = (const float*)d_in[2];
    float* o = (float*)d_out;
    dim3 grid(WW / TSX, HH / TSY);
    local_attn_mfma<<<grid, dim3(NTHREADS), 0, stream>>>(main_in, ref_in, val_in, o);
}

// Round 7
// 82.559 us; speedup vs baseline: 1.0281x; 1.0281x over previous
//
#include <hip/hip_runtime.h>

#define HH 256
#define WW 256
#define CC 32
#define K 7
#define RAD 3
#define TSX 16
#define TSY 8
#define HX (TSX + K - 1)   /* 22 */
#define HY (TSY + K - 1)   /* 14 */
#define NPIX (HX * HY)     /* 308 */
#define REF_ST 40          /* halfs per pixel (32 ch + 8 pad), 80 B */
#define REF_SZ 12800       /* >= max masked OOB read (pixel 317)*40 + 40 */
#define VT_ST 344          /* halfs per channel row of V^T (14*24 + 8 pad) */
#define VT_SZ 11008        /* 32 * 344 */
#define NTHREADS 256

typedef _Float16 half_t;
typedef _Float16 h8 __attribute__((ext_vector_type(8)));
typedef float f4 __attribute__((ext_vector_type(4)));
typedef unsigned int u32;
typedef u32 u4v __attribute__((ext_vector_type(4)));
typedef u32 u2v __attribute__((ext_vector_type(2)));

union Frag { h8 h; u4v u; u32 w[4]; };

static __device__ inline u32 pkrtz_u(float x, float y) {
    auto t = __builtin_amdgcn_cvt_pkrtz(x, y);
    u32 r; __builtin_memcpy(&r, &t, sizeof(r)); return r;
}

__global__ __launch_bounds__(NTHREADS) void local_attn_mfma(
    const float* __restrict__ main_in,
    const float* __restrict__ ref_in,
    const float* __restrict__ val_in,
    float* __restrict__ out)
{
    // s_ref: [pixel][ch] fp16, stride 40 halfs. NOT zero-initialized: garbage
    //        pixels feed only band-masked C-rows (post-MFMA ternary discards;
    //        per-row dots mean NaN cannot leak into unmasked rows).
    // s_valT: [ch][hy][x] fp16 (x-stride 24, ch-stride 344). Only the pad
    //        cells PV can read (x=22,23 + row tails) are zeroed — 1152 halfs
    //        instead of the full 11008.
    __shared__ half_t s_ref[REF_SZ];
    __shared__ half_t s_valT[VT_SZ];

    const int tid = threadIdx.x;
    const int ox = blockIdx.x * TSX;
    const int oy = blockIdx.y * TSY;

    // ---- Zero PV-readable pad cells of s_valT (u32 halves-pairs, 576 total) ----
    for (int j = tid; j < 576; j += NTHREADS) {
        const int ch = j / 18;
        const int r = j - ch * 18;
        const int e = (r < 14) ? (ch * VT_ST + r * 24 + 22)
                               : (ch * VT_ST + 336 + (r - 14) * 2);
        *(u32*)(s_valT + e) = 0u;
    }

    // ---- Stage halo: ref -> s_ref (b64 writes), val -> s_valT (transposed u16) ----
    for (int idx = tid; idx < NPIX * 8; idx += NTHREADS) {
        const int pix = idx >> 3;
        const int c4 = idx & 7;
        const int hy = pix / HX;
        const int wx = pix - hy * HX;
        const int gh = oy + hy - RAD;
        const int gw = ox + wx - RAD;
        u32 r0 = 0, r1 = 0;
        f4 v = {0.f, 0.f, 0.f, 0.f};
        if ((unsigned)gh < (unsigned)HH && (unsigned)gw < (unsigned)WW) {
            const int goff = (gh * WW + gw) * CC + c4 * 4;
            f4 rv = *(const f4*)(ref_in + goff);
            v = *(const f4*)(val_in + goff);
            r0 = pkrtz_u(rv.x, rv.y);
            r1 = pkrtz_u(rv.z, rv.w);
        }
        u2v rw = {r0, r1};
        *(u2v*)(s_ref + pix * REF_ST + c4 * 4) = rw;
        const int ch = c4 * 4;
        const int vo = hy * 24 + wx;
        s_valT[(ch + 0) * VT_ST + vo] = (half_t)v.x;
        s_valT[(ch + 1) * VT_ST + vo] = (half_t)v.y;
        s_valT[(ch + 2) * VT_ST + vo] = (half_t)v.z;
        s_valT[(ch + 3) * VT_ST + vo] = (half_t)v.w;
    }
    __syncthreads();

    // ---- Per-wave: 2 image rows, 16 queries each, all via MFMA ----
    const int lane = tid & 63;
    const int i = lane & 15;          // query column / A-row index
    const int g = lane >> 4;          // k-octet group
    const int k0 = 8 * (i >> 2) + (i & 3);  // permuted A-row -> key map (P lane-local)
    const int d0 = 8 * g - i;         // key - query offset for reg 0 of c1a
    const int wv = tid >> 6;

#pragma unroll 1
    for (int rrow = 0; rrow < 2; ++rrow) {
        const int hl = 2 * wv + rrow;
        const int h = oy + hl;

        // Q fragment (B-operand): lane holds query pixel (ox+i), channels 8g..8g+7
        const float* qp = main_in + (h * WW + ox + i) * CC + g * 8;
        f4 q0 = *(const f4*)qp;
        f4 q1 = *(const f4*)(qp + 4);
        Frag qf;
        qf.w[0] = pkrtz_u(q0.x, q0.y);
        qf.w[1] = pkrtz_u(q0.z, q0.w);
        qf.w[2] = pkrtz_u(q1.x, q1.y);
        qf.w[3] = pkrtz_u(q1.z, q1.w);

        // Scores: per di, C[key, query] = K-rows x Q. Band-mask to -1e30.
        float sc[K][8];
#pragma unroll
        for (int di = 0; di < K; ++di) {
            const int rb = (hl + di) * HX;
            const int p0 = rb + k0;
            const int p1 = p0 + 4;
            Frag a0, a1;
            a0.u = *(const u4v*)(s_ref + p0 * REF_ST + g * 8);
            a1.u = *(const u4v*)(s_ref + p1 * REF_ST + g * 8);
            f4 c1a = {0.f, 0.f, 0.f, 0.f};
            f4 c1b = {0.f, 0.f, 0.f, 0.f};
            c1a = __builtin_amdgcn_mfma_f32_16x16x32_f16(a0.h, qf.h, c1a, 0, 0, 0);
            c1b = __builtin_amdgcn_mfma_f32_16x16x32_f16(a1.h, qf.h, c1b, 0, 0, 0);
#pragma unroll
            for (int r = 0; r < 4; ++r) {
                sc[di][r]     = ((unsigned)(d0 + r) <= 6u)     ? c1a[r] : -1e30f;
                sc[di][r + 4] = ((unsigned)(d0 + 4 + r) <= 6u) ? c1b[r] : -1e30f;
            }
        }

        // Softmax over 49 in-band entries (image-OOB keys staged as 0 -> score 0)
        float mx = -1e30f;
#pragma unroll
        for (int di = 0; di < K; ++di)
#pragma unroll
            for (int j = 0; j < 8; ++j) mx = fmaxf(mx, sc[di][j]);
        mx = fmaxf(mx, __shfl_xor(mx, 16));
        mx = fmaxf(mx, __shfl_xor(mx, 32));
        float lsum = 0.f;
#pragma unroll
        for (int di = 0; di < K; ++di)
#pragma unroll
            for (int j = 0; j < 8; ++j) {
                const float ev = __expf(sc[di][j] - mx);
                sc[di][j] = ev;
                lsum += ev;
            }
        lsum += __shfl_xor(lsum, 16);
        lsum += __shfl_xor(lsum, 32);
        const float invl = 1.0f / lsum;

        // PV: C2[ch, query] += V^T(A) x P(B), accumulated over di
        f4 c2a = {0.f, 0.f, 0.f, 0.f};
        f4 c2b = {0.f, 0.f, 0.f, 0.f};
#pragma unroll
        for (int di = 0; di < K; ++di) {
            Frag pf;   // B-frag: half j = P[key 8g+j] (lane-local via k0 permutation)
            pf.w[0] = pkrtz_u(sc[di][0], sc[di][1]);
            pf.w[1] = pkrtz_u(sc[di][2], sc[di][3]);
            pf.w[2] = pkrtz_u(sc[di][4], sc[di][5]);
            pf.w[3] = pkrtz_u(sc[di][6], sc[di][7]);
            const int ro = (hl + di) * 24 + g * 8;
            Frag va0, va1;
            va0.u = *(const u4v*)(s_valT + i * VT_ST + ro);          // ch i, keys 8g..8g+7
            va1.u = *(const u4v*)(s_valT + (i + 16) * VT_ST + ro);   // ch i+16
            c2a = __builtin_amdgcn_mfma_f32_16x16x32_f16(va0.h, pf.h, c2a, 0, 0, 0);
            c2b = __builtin_amdgcn_mfma_f32_16x16x32_f16(va1.h, pf.h, c2b, 0, 0, 0);
        }

        // C2 lane: col = query i, rows = ch 4g+r (frag a) / 16+4g+r (frag b)
        float* op = out + (h * WW + ox + i) * CC;
        f4 o0 = {c2a[0] * invl, c2a[1] * invl, c2a[2] * invl, c2a[3] * invl};
        f4 o1 = {c2b[0] * invl, c2b[1] * invl, c2b[2] * invl, c2b[3] * invl};
        *(f4*)(op + 4 * g) = o0;
        *(f4*)(op + 16 + 4 * g) = o1;
    }
}

extern "C" void kernel_launch(void* const* d_in, const int* in_sizes, int n_in,
                              void* d_out, int out_size, void* d_ws, size_t ws_size,
                              hipStream_t stream) {
    const float* main_in = (const float*)d_in[0];
    const float* ref_in  = (const float*)d_in[1];
    const float* val_in  = (const float*)d_in[2];
    float* o = (float*)d_out;
    dim3 grid(WW / TSX, HH / TSY);
    local_attn_mfma<<<grid, dim3(NTHREADS), 0, stream>>>(main_in, ref_in, val_in, o);
}